// Round 1
// baseline (956.380 us; speedup 1.0000x reference)
//
#include <hip/hip_runtime.h>
#include <hip/hip_bf16.h>

#define M_DIM 16384   // 8 * 2048
#define N_DIM 4096
#define K_DIM 4096

typedef unsigned short u16;
typedef __attribute__((ext_vector_type(8))) short  bf16x8;
typedef __attribute__((ext_vector_type(8))) u16    u16x8;
typedef __attribute__((ext_vector_type(4))) float  f32x4;

// fp32 -> bf16 round-to-nearest-even
__device__ __forceinline__ u16 f2bf(float f) {
    unsigned u = __float_as_uint(f);
    u += 0x7fffu + ((u >> 16) & 1u);
    return (u16)(u >> 16);
}

// ---- prepass: A fp32 -> bf16 (vectorized, 8 elems/thread/iter) ----
__global__ void cvt_a_kernel(const float* __restrict__ in, u16* __restrict__ out, int n8) {
    int stride = gridDim.x * blockDim.x;
    for (int i = blockIdx.x * blockDim.x + threadIdx.x; i < n8; i += stride) {
        float4 v0 = ((const float4*)in)[2 * i];
        float4 v1 = ((const float4*)in)[2 * i + 1];
        u16x8 r;
        r[0] = f2bf(v0.x); r[1] = f2bf(v0.y); r[2] = f2bf(v0.z); r[3] = f2bf(v0.w);
        r[4] = f2bf(v1.x); r[5] = f2bf(v1.y); r[6] = f2bf(v1.z); r[7] = f2bf(v1.w);
        ((u16x8*)out)[i] = r;
    }
}

// ---- prepass: W int32 -> dequant bf16 ----
__global__ void cvt_w_kernel(const int* __restrict__ q, u16* __restrict__ out,
                             const float* __restrict__ sc_p, const int* __restrict__ zp_p,
                             int n8) {
    float sc = sc_p[0];
    float zp = (float)zp_p[0];
    int stride = gridDim.x * blockDim.x;
    for (int i = blockIdx.x * blockDim.x + threadIdx.x; i < n8; i += stride) {
        int4 q0 = ((const int4*)q)[2 * i];
        int4 q1 = ((const int4*)q)[2 * i + 1];
        u16x8 r;
        r[0] = f2bf(((float)q0.x - zp) * sc); r[1] = f2bf(((float)q0.y - zp) * sc);
        r[2] = f2bf(((float)q0.z - zp) * sc); r[3] = f2bf(((float)q0.w - zp) * sc);
        r[4] = f2bf(((float)q1.x - zp) * sc); r[5] = f2bf(((float)q1.y - zp) * sc);
        r[6] = f2bf(((float)q1.z - zp) * sc); r[7] = f2bf(((float)q1.w - zp) * sc);
        ((u16x8*)out)[i] = r;
    }
}

// ---- main GEMM: m97 structure. C[m][n] = sum_k A[m][k]*B[n][k] + bias[n]
// 128x128 tile, BK=64, 256 threads (4 waves, 2x2), global_load_lds width=16,
// 2 barriers per K-step, mfma_f32_16x16x32_bf16, 4x4 fragments per wave.
__global__ __launch_bounds__(256)
void gemm_bt_kernel(const u16* __restrict__ A, const u16* __restrict__ B,
                    const int* __restrict__ qb, const float* __restrict__ bsc_p,
                    const int* __restrict__ bzp_p, float* __restrict__ C) {
    __shared__ __align__(16) u16 As[128 * 64];
    __shared__ __align__(16) u16 Bs[128 * 64];

    // bijective XCD swizzle (nwg = 4096, divisible by 8)
    int nwg = gridDim.x;
    int cpx = nwg >> 3;
    int bid = blockIdx.x;
    int swz = (bid & 7) * cpx + (bid >> 3);
    int bm = swz / (N_DIM / 128);
    int bn = swz % (N_DIM / 128);
    int m0 = bm * 128, n0 = bn * 128;

    int tid  = threadIdx.x;
    int wv   = tid >> 6;
    int lane = tid & 63;
    int wr   = wv >> 1;   // wave row (0..1), each wave owns 64x64
    int wc   = wv & 1;    // wave col (0..1)

    const u16* Ag = A + (size_t)m0 * K_DIM;
    const u16* Bg = B + (size_t)n0 * K_DIM;

    f32x4 acc[4][4] = {};

    for (int k0 = 0; k0 < K_DIM; k0 += 64) {
#pragma unroll
        for (int j = 0; j < 4; ++j) {
            int slot = wv * 4 + j;                 // 0..15, wave-uniform
            int row  = slot * 8 + (lane >> 3);     // 0..127
            int col  = (lane & 7) * 8;             // bf16 column within BK=64
            __builtin_amdgcn_global_load_lds(
                (const __attribute__((address_space(1))) void*)(Ag + (size_t)row * K_DIM + k0 + col),
                (__attribute__((address_space(3))) void*)(As + slot * 512),
                16, 0, 0);
            __builtin_amdgcn_global_load_lds(
                (const __attribute__((address_space(1))) void*)(Bg + (size_t)row * K_DIM + k0 + col),
                (__attribute__((address_space(3))) void*)(Bs + slot * 512),
                16, 0, 0);
        }
        __syncthreads();   // drains vmcnt(0): LDS data ready

#pragma unroll
        for (int kk = 0; kk < 64; kk += 32) {
            bf16x8 af[4], bfr[4];
#pragma unroll
            for (int mi = 0; mi < 4; ++mi) {
                int row = wr * 64 + mi * 16 + (lane & 15);
                af[mi] = *(const bf16x8*)(As + row * 64 + kk + (lane >> 4) * 8);
            }
#pragma unroll
            for (int ni = 0; ni < 4; ++ni) {
                int row = wc * 64 + ni * 16 + (lane & 15);
                bfr[ni] = *(const bf16x8*)(Bs + row * 64 + kk + (lane >> 4) * 8);
            }
#pragma unroll
            for (int mi = 0; mi < 4; ++mi)
#pragma unroll
                for (int ni = 0; ni < 4; ++ni)
                    acc[mi][ni] = __builtin_amdgcn_mfma_f32_16x16x32_bf16(
                        af[mi], bfr[ni], acc[mi][ni], 0, 0, 0);
        }
        __syncthreads();   // protect LDS before next stage
    }

    // epilogue: bias dequant + store
    float bsc = bsc_p[0];
    float bzp = (float)bzp_p[0];
#pragma unroll
    for (int ni = 0; ni < 4; ++ni) {
        int col = n0 + wc * 64 + ni * 16 + (lane & 15);
        float bias = ((float)qb[col] - bzp) * bsc;
#pragma unroll
        for (int mi = 0; mi < 4; ++mi) {
            int row = m0 + wr * 64 + mi * 16 + (lane >> 4) * 4;
#pragma unroll
            for (int i = 0; i < 4; ++i)
                C[(size_t)(row + i) * N_DIM + col] = acc[mi][ni][i] + bias;
        }
    }
}

// ---- fallback (only if ws too small): correct, slow ----
__global__ void gemm_fallback_kernel(const float* __restrict__ A, const int* __restrict__ Wq,
                                     const float* __restrict__ wsc_p, const int* __restrict__ wzp_p,
                                     const int* __restrict__ qb, const float* __restrict__ bsc_p,
                                     const int* __restrict__ bzp_p, float* __restrict__ C) {
    int m = blockIdx.y;
    int n = blockIdx.x * 256 + threadIdx.x;
    float zp = (float)wzp_p[0];
    float sc = wsc_p[0];
    __shared__ float Arow[512];
    float acc = 0.f;
    for (int k0 = 0; k0 < K_DIM; k0 += 512) {
        __syncthreads();
        for (int t = threadIdx.x; t < 512; t += 256)
            Arow[t] = A[(size_t)m * K_DIM + k0 + t];
        __syncthreads();
        const int4* wp = (const int4*)(Wq + (size_t)n * K_DIM + k0);
        for (int kk = 0; kk < 512; kk += 4) {
            int4 q = wp[kk >> 2];
            acc += Arow[kk]     * ((float)q.x - zp);
            acc += Arow[kk + 1] * ((float)q.y - zp);
            acc += Arow[kk + 2] * ((float)q.z - zp);
            acc += Arow[kk + 3] * ((float)q.w - zp);
        }
    }
    acc *= sc;
    acc += ((float)qb[n] - (float)bzp_p[0]) * bsc_p[0];
    C[(size_t)m * N_DIM + n] = acc;
}

extern "C" void kernel_launch(void* const* d_in, const int* in_sizes, int n_in,
                              void* d_out, int out_size, void* d_ws, size_t ws_size,
                              hipStream_t stream) {
    (void)in_sizes; (void)n_in; (void)out_size;
    const float* input = (const float*)d_in[0];
    const int*   qw    = (const int*)d_in[1];
    const float* wsc   = (const float*)d_in[2];
    const int*   wzp   = (const int*)d_in[3];
    const int*   qb    = (const int*)d_in[4];
    const float* bsc   = (const float*)d_in[5];
    const int*   bzp   = (const int*)d_in[6];
    float* out = (float*)d_out;

    size_t needA = (size_t)M_DIM * K_DIM * sizeof(u16);   // 128 MB
    size_t needW = (size_t)N_DIM * K_DIM * sizeof(u16);   //  32 MB

    if (ws_size >= needA + needW) {
        u16* Abf = (u16*)d_ws;
        u16* Wbf = (u16*)((char*)d_ws + needA);
        cvt_a_kernel<<<4096, 256, 0, stream>>>(input, Abf, M_DIM * K_DIM / 8);
        cvt_w_kernel<<<2048, 256, 0, stream>>>(qw, Wbf, wsc, wzp, N_DIM * K_DIM / 8);
        gemm_bt_kernel<<<(M_DIM / 128) * (N_DIM / 128), 256, 0, stream>>>(
            Abf, Wbf, qb, bsc, bzp, out);
    } else {
        dim3 grid(N_DIM / 256, M_DIM);
        gemm_fallback_kernel<<<grid, 256, 0, stream>>>(input, qw, wsc, wzp, qb, bsc, bzp, out);
    }
}

// Round 2
// 619.196 us; speedup vs baseline: 1.5446x; 1.5446x over previous
//
#include <hip/hip_runtime.h>
#include <hip/hip_bf16.h>

#define M_DIM 16384   // 8 * 2048
#define N_DIM 4096
#define K_DIM 4096
#define BK 32
#define NKT (K_DIM / BK)   // 128 K-tiles

typedef unsigned short u16;
typedef __attribute__((ext_vector_type(8))) short  bf16x8;
typedef __attribute__((ext_vector_type(8))) u16    u16x8;
typedef __attribute__((ext_vector_type(4))) float  f32x4;

#define AS1 __attribute__((address_space(1)))
#define AS3 __attribute__((address_space(3)))

// fp32 -> bf16 round-to-nearest-even
__device__ __forceinline__ u16 f2bf(float f) {
    unsigned u = __float_as_uint(f);
    u += 0x7fffu + ((u >> 16) & 1u);
    return (u16)(u >> 16);
}

// ---- prepass: A fp32 -> bf16 ----
__global__ void cvt_a_kernel(const float* __restrict__ in, u16* __restrict__ out, int n8) {
    int stride = gridDim.x * blockDim.x;
    for (int i = blockIdx.x * blockDim.x + threadIdx.x; i < n8; i += stride) {
        float4 v0 = ((const float4*)in)[2 * i];
        float4 v1 = ((const float4*)in)[2 * i + 1];
        u16x8 r;
        r[0] = f2bf(v0.x); r[1] = f2bf(v0.y); r[2] = f2bf(v0.z); r[3] = f2bf(v0.w);
        r[4] = f2bf(v1.x); r[5] = f2bf(v1.y); r[6] = f2bf(v1.z); r[7] = f2bf(v1.w);
        ((u16x8*)out)[i] = r;
    }
}

// ---- prepass: W int32 -> dequant bf16 ----
__global__ void cvt_w_kernel(const int* __restrict__ q, u16* __restrict__ out,
                             const float* __restrict__ sc_p, const int* __restrict__ zp_p,
                             int n8) {
    float sc = sc_p[0];
    float zp = (float)zp_p[0];
    int stride = gridDim.x * blockDim.x;
    for (int i = blockIdx.x * blockDim.x + threadIdx.x; i < n8; i += stride) {
        int4 q0 = ((const int4*)q)[2 * i];
        int4 q1 = ((const int4*)q)[2 * i + 1];
        u16x8 r;
        r[0] = f2bf(((float)q0.x - zp) * sc); r[1] = f2bf(((float)q0.y - zp) * sc);
        r[2] = f2bf(((float)q0.z - zp) * sc); r[3] = f2bf(((float)q0.w - zp) * sc);
        r[4] = f2bf(((float)q1.x - zp) * sc); r[5] = f2bf(((float)q1.y - zp) * sc);
        r[6] = f2bf(((float)q1.z - zp) * sc); r[7] = f2bf(((float)q1.w - zp) * sc);
        ((u16x8*)out)[i] = r;
    }
}

// ---- 256x256 8-phase GEMM, ring-of-4 K-slots (BK=32), counted vmcnt ----
// C[m][n] = sum_k A[m][k]*B[n][k] + bias[n].
// 512 threads = 8 waves (2M x 4N); per-wave tile 128x64; acc = f32x4[8][4].
// LDS: 4 slots x (A 256x32 + B 256x32) bf16 = 128 KiB.
// Swizzle: 16B-slot ^= (row>>1)&3  (read side == pre-swizzled global source).
__global__ __launch_bounds__(512, 2)
void gemm8p_kernel(const u16* __restrict__ A, const u16* __restrict__ B,
                   const int* __restrict__ qb, const float* __restrict__ bsc_p,
                   const int* __restrict__ bzp_p, float* __restrict__ C) {
    __shared__ __align__(16) u16 lds[4 * 16384];   // 128 KiB

    // XCD-bijective swizzle + 8x4 supertiles for L2 reuse (nwg=1024, %8==0)
    const int nwg = gridDim.x;
    const int cpx = nwg >> 3;                // 128
    const int bid = blockIdx.x;
    const int swz = (bid & 7) * cpx + (bid >> 3);
    const int st = swz >> 5, wi = swz & 31;  // 32 supertiles of 8x4 blocks
    const int bm = (st >> 2) * 8 + (wi >> 2);   // 0..63
    const int bn = (st & 3) * 4 + (wi & 3);     // 0..15
    const int m0 = bm * 256, n0 = bn * 256;

    const int tid  = threadIdx.x;
    const int wv   = tid >> 6;
    const int lane = tid & 63;
    const int wr   = wv >> 2;     // 0..1 : wave row (128 M-rows each)
    const int wcn  = wv & 3;      // 0..3 : wave col (64 N-cols each)
    const int l15  = lane & 15;

    // per-lane constant swizzled k-slot offset for fragment reads (u16 units)
    const int koff = (((lane >> 4) ^ ((lane >> 1) & 3)) << 3);

    // staging constants: lane writes LDS linearly; source col pre-swizzled
    const int srow = tid >> 2;                               // 0..127 (+128*i)
    const int gcol = (((tid & 3) ^ ((tid >> 3) & 3)) << 3);  // pre-swizzled col
    const u16* AgT = A + (size_t)(m0 + srow) * K_DIM + gcol;
    const u16* BgT = B + (size_t)(n0 + srow) * K_DIM + gcol;
    const int wvo = wv << 9;     // wv*512 u16 = 1024 B per wave per instr

    f32x4 acc[8][4] = {};

    auto STAGE_A = [&](int ns, int k3) {
#pragma unroll
        for (int i = 0; i < 2; ++i)
            __builtin_amdgcn_global_load_lds(
                (const AS1 void*)(AgT + (size_t)i * 128 * K_DIM + k3),
                (AS3 void*)(lds + ns * 16384 + i * 4096 + wvo), 16, 0, 0);
    };
    auto STAGE_B = [&](int ns, int k3) {
#pragma unroll
        for (int i = 0; i < 2; ++i)
            __builtin_amdgcn_global_load_lds(
                (const AS1 void*)(BgT + (size_t)i * 128 * K_DIM + k3),
                (AS3 void*)(lds + ns * 16384 + 8192 + i * 4096 + wvo), 16, 0, 0);
    };

    // ---- prologue: stage K-tiles 0,1,2 into slots 0,1,2 (12 loads) ----
    STAGE_A(0, 0);      STAGE_B(0, 0);
    STAGE_A(1, BK);     STAGE_B(1, BK);
    STAGE_A(2, 2 * BK); STAGE_B(2, 2 * BK);
    asm volatile("s_waitcnt vmcnt(8)" ::: "memory");   // tile 0 landed
    __builtin_amdgcn_s_barrier();
    __builtin_amdgcn_sched_barrier(0);

#pragma unroll 4
    for (int u = 0; u < NKT; ++u) {
        const int cs = u & 3;
        const u16* Asl = lds + cs * 16384;
        const u16* Bsl = Asl + 8192;
        const bool pf = (u + 3) < NKT;
        const int ns = (u + 3) & 3;
        const int k3 = (u + 3) * BK;

        bf16x8 af[4], bfr[4];

        // ======== phase A: m-frags 0-3 x n-frags 0-3, stage A(u+3) ========
#pragma unroll
        for (int mi = 0; mi < 4; ++mi) {
            int row = wr * 128 + mi * 16 + l15;
            af[mi] = *(const bf16x8*)(Asl + row * 32 + koff);
        }
#pragma unroll
        for (int ni = 0; ni < 4; ++ni) {
            int row = wcn * 64 + ni * 16 + l15;
            bfr[ni] = *(const bf16x8*)(Bsl + row * 32 + koff);
        }
        if (pf) STAGE_A(ns, k3);
        __builtin_amdgcn_s_barrier();
        asm volatile("s_waitcnt lgkmcnt(0)" ::: "memory");
        __builtin_amdgcn_sched_barrier(0);
        __builtin_amdgcn_s_setprio(1);
#pragma unroll
        for (int mi = 0; mi < 4; ++mi)
#pragma unroll
            for (int ni = 0; ni < 4; ++ni)
                acc[mi][ni] = __builtin_amdgcn_mfma_f32_16x16x32_bf16(
                    af[mi], bfr[ni], acc[mi][ni], 0, 0, 0);
        __builtin_amdgcn_s_setprio(0);
        __builtin_amdgcn_s_barrier();
        __builtin_amdgcn_sched_barrier(0);

        // ======== phase B: m-frags 4-7 (reuse bfr), stage B(u+3) ========
#pragma unroll
        for (int mi = 0; mi < 4; ++mi) {
            int row = wr * 128 + 64 + mi * 16 + l15;
            af[mi] = *(const bf16x8*)(Asl + row * 32 + koff);
        }
        if (pf) STAGE_B(ns, k3);
        __builtin_amdgcn_s_barrier();
        asm volatile("s_waitcnt lgkmcnt(0)" ::: "memory");
        __builtin_amdgcn_sched_barrier(0);
        __builtin_amdgcn_s_setprio(1);
#pragma unroll
        for (int mi = 0; mi < 4; ++mi)
#pragma unroll
            for (int ni = 0; ni < 4; ++ni)
                acc[mi + 4][ni] = __builtin_amdgcn_mfma_f32_16x16x32_bf16(
                    af[mi], bfr[ni], acc[mi + 4][ni], 0, 0, 0);
        __builtin_amdgcn_s_setprio(0);
        // K-tile boundary: ensure tile u+1 landed before any wave reads it.
        // Steady state: 12 outstanding (u+1,u+2,u+3) -> drain oldest 4.
        if (u < NKT - 3)       asm volatile("s_waitcnt vmcnt(8)" ::: "memory");
        else if (u == NKT - 3) asm volatile("s_waitcnt vmcnt(4)" ::: "memory");
        else if (u == NKT - 2) asm volatile("s_waitcnt vmcnt(0)" ::: "memory");
        __builtin_amdgcn_s_barrier();
        __builtin_amdgcn_sched_barrier(0);
    }

    // ---- epilogue: bias + store ----
    float bsc = bsc_p[0];
    float bzp = (float)bzp_p[0];
#pragma unroll
    for (int ni = 0; ni < 4; ++ni) {
        int col = n0 + wcn * 64 + ni * 16 + l15;
        float bias = ((float)qb[col] - bzp) * bsc;
#pragma unroll
        for (int mi = 0; mi < 8; ++mi) {
            int row = m0 + wr * 128 + mi * 16 + (lane >> 4) * 4;
#pragma unroll
            for (int i = 0; i < 4; ++i)
                C[(size_t)(row + i) * N_DIM + col] = acc[mi][ni][i] + bias;
        }
    }
}

// ---- fallback (only if ws too small): correct, slow ----
__global__ void gemm_fallback_kernel(const float* __restrict__ A, const int* __restrict__ Wq,
                                     const float* __restrict__ wsc_p, const int* __restrict__ wzp_p,
                                     const int* __restrict__ qb, const float* __restrict__ bsc_p,
                                     const int* __restrict__ bzp_p, float* __restrict__ C) {
    int m = blockIdx.y;
    int n = blockIdx.x * 256 + threadIdx.x;
    float zp = (float)wzp_p[0];
    float sc = wsc_p[0];
    __shared__ float Arow[512];
    float acc = 0.f;
    for (int k0 = 0; k0 < K_DIM; k0 += 512) {
        __syncthreads();
        for (int t = threadIdx.x; t < 512; t += 256)
            Arow[t] = A[(size_t)m * K_DIM + k0 + t];
        __syncthreads();
        const int4* wp = (const int4*)(Wq + (size_t)n * K_DIM + k0);
        for (int kk = 0; kk < 512; kk += 4) {
            int4 q = wp[kk >> 2];
            acc += Arow[kk]     * ((float)q.x - zp);
            acc += Arow[kk + 1] * ((float)q.y - zp);
            acc += Arow[kk + 2] * ((float)q.z - zp);
            acc += Arow[kk + 3] * ((float)q.w - zp);
        }
    }
    acc *= sc;
    acc += ((float)qb[n] - (float)bzp_p[0]) * bsc_p[0];
    C[(size_t)m * N_DIM + n] = acc;
}

extern "C" void kernel_launch(void* const* d_in, const int* in_sizes, int n_in,
                              void* d_out, int out_size, void* d_ws, size_t ws_size,
                              hipStream_t stream) {
    (void)in_sizes; (void)n_in; (void)out_size;
    const float* input = (const float*)d_in[0];
    const int*   qw    = (const int*)d_in[1];
    const float* wsc   = (const float*)d_in[2];
    const int*   wzp   = (const int*)d_in[3];
    const int*   qb    = (const int*)d_in[4];
    const float* bsc   = (const float*)d_in[5];
    const int*   bzp   = (const int*)d_in[6];
    float* out = (float*)d_out;

    size_t needA = (size_t)M_DIM * K_DIM * sizeof(u16);   // 128 MB
    size_t needW = (size_t)N_DIM * K_DIM * sizeof(u16);   //  32 MB

    if (ws_size >= needA + needW) {
        u16* Abf = (u16*)d_ws;
        u16* Wbf = (u16*)((char*)d_ws + needA);
        cvt_a_kernel<<<4096, 256, 0, stream>>>(input, Abf, M_DIM * K_DIM / 8);
        cvt_w_kernel<<<2048, 256, 0, stream>>>(qw, Wbf, wsc, wzp, N_DIM * K_DIM / 8);
        gemm8p_kernel<<<(M_DIM / 256) * (N_DIM / 256), 512, 0, stream>>>(
            Abf, Wbf, qb, bsc, bzp, out);
    } else {
        dim3 grid(N_DIM / 256, M_DIM);
        gemm_fallback_kernel<<<grid, 256, 0, stream>>>(input, qw, wsc, wzp, qb, bsc, bzp, out);
    }
}